// Round 10
// baseline (258.153 us; speedup 1.0000x reference)
//
#include <hip/hip_runtime.h>
#include <math.h>

// EquiTritonModel: N=10000 nodes, E=160000 edges, D=32, H=16, NB=16.
// R22 -> R23: global_atomic_pk_add_f32 doesn't exist on gfx950 (compile
// fail) and f16/bf16 packed atomics would inject ~1e-3..1e-2 abs error
// => the 27us atomic floor (64 dwords/edge @ ~380G RMW/s) stands.
// Cross-round algebra (R17 vs R19, consistent OH≈74us) puts edge2 at
// ~32us — the biggest untouched piece. Change: move the per-edge
// H1/H4 G-transform INTO edge1 (sines already computed there; G-rows
// built in LDS BEFORE any atomics so the start-of-kernel barrier is
// harmless), store (H1,H4) float2/lane-edge (20.5MB coalesced) + u
// float4/edge (2.6MB). zacc switches to interleaved [n*64+4t+c] so
// edge2 gathers ONE float4/lane. New edge2 = pure stream: ei[src] +
// float2 + broadcast float4 + gather float4 + 5 FMA. No trig/shuffles.

namespace {
constexpr int   NATOMS   = 100;
constexpr float PI_F     = 3.14159265358979323846f;
constexpr float INV4PI_F = 0.28209479177387814f;   // 1/sqrt(4*pi)
constexpr float SQRT3_F  = 1.7320508075688772f;
constexpr float CUT_F    = 6.0f;
constexpr float BASIS_C  = 2.3094010767585034f;    // sqrt(2/6)*sqrt(16)
constexpr float N0_F     = 0.17677669529663687f;   // 1/sqrt(32)
constexpr float K0_F = INV4PI_F * N0_F * 0.0625f;  // z0 scale incl /DEG
constexpr float K1_F = SQRT3_F * INV4PI_F * N0_F * 0.0625f;
constexpr float P2SC = INV4PI_F * N0_F * (1.0f / 64.0f);
}

__device__ __forceinline__ float silu_fast(float x) {
  return x / (1.0f + __expf(-x));
}

__device__ __forceinline__ float block_reduce_sum(float v) {
  #pragma unroll
  for (int o = 32; o > 0; o >>= 1) v += __shfl_down(v, o, 64);
  __shared__ float ls[8];
  int lane = threadIdx.x & 63;
  int w    = threadIdx.x >> 6;
  if (lane == 0) ls[w] = v;
  __syncthreads();
  float s = 0.f;
  if (threadIdx.x == 0) {
    int nw = (blockDim.x + 63) >> 6;
    for (int i = 0; i < nw; ++i) s += ls[i];
  }
  return s;
}

// ---------------------------------------------------------------------------
// table_kernel: blocks [0,NATOMS) -> TI tables; blocks >= NATOMS zero zacc
// (N*64 floats as float4) — no hipMemset needed.
// ---------------------------------------------------------------------------
__global__ void __launch_bounds__(256)
table_kernel(const float* __restrict__ atom_emb,
             const float* __restrict__ fc0_w2,
             float* __restrict__ TI,
             float4* __restrict__ zero4,   // zacc as float4
             float* __restrict__ out,
             int NZ4) {
  int b = blockIdx.x;
  int tt = threadIdx.x;
  if (b < NATOMS) {
    int j = tt >> 4;
    int h = tt & 15;
    float s0 = 0.f, s1 = 0.f;
    #pragma unroll
    for (int d = 0; d < 32; ++d) {
      float x = atom_emb[b * 32 + d];
      s0 = fmaf(x, fc0_w2[j * 1024 + d * 16 + h], s0);
      s1 = fmaf(x, fc0_w2[j * 1024 + 512 + d * 16 + h], s1);
    }
    TI[b * 512 + j * 32 + 2 * h]     = s0;
    TI[b * 512 + j * 32 + 2 * h + 1] = s1;
    if (b == 0 && tt == 0) *out = 0.f;
  } else {
    int idx = (b - NATOMS) * 256 + tt;
    if (idx < NZ4) zero4[idx] = make_float4(0.f, 0.f, 0.f, 0.f);
  }
}

// ---------------------------------------------------------------------------
// edge_kernel: 16 groups x 16 lanes; group g handles edges b*32+g and
// b*32+16+g (2-edge ILP pipeline). Computes BOTH MLP heads (shared sine
// recurrence), TI contraction, and the per-edge H1/H4 G-transform.
// Outputs:
//   zacc[dst*64 + 4t + {0,1,2,3}] += {K0*u0, m1*ux, m1*uy, m1*uz} (atomics)
//   hbuf2[e*16+t] = (H1,H4)   (coalesced float2)
//   ubuf[e]       = unit vec  (float4, t==0)
// G-rows live in LDS, built BEFORE any atomics (barrier at kernel start
// only — no post-atomic drain, the R18 trap).
// ---------------------------------------------------------------------------
__global__ void __launch_bounds__(256)
edge_kernel(const int* __restrict__ ei,
            const float* __restrict__ coords,
            const int* __restrict__ an,
            const float* __restrict__ TI,
            const float* __restrict__ fc0_w1,
            const float* __restrict__ fc1_w1,
            const float* __restrict__ fc1_w2,
            const float* __restrict__ w_readout,
            float* __restrict__ zacc,
            float2* __restrict__ hbuf2,
            float4* __restrict__ ubuf,
            int E) {
  // G-tables, k-major so the transform loop reads conflict-free:
  // ggs[k*16 + h] = G1[h,k];  ggs[256 + k*16 + h] = G4[h,k]
  __shared__ float ggs[512];
  {
    int m = threadIdx.x >> 4;         // hidden index k
    int h = threadIdx.x & 15;
    float g1 = 0.f, g4 = 0.f;
    #pragma unroll
    for (int k = 0; k < 16; ++k) {
      float r = w_readout[k];
      g1 = fmaf(fc1_w2[m * 1024 + h * 16 + k], r, g1);
      g4 = fmaf(fc1_w2[m * 1024 + 768 + h * 16 + k], r, g4);
    }
    ggs[m * 16 + h]       = g1;
    ggs[256 + m * 16 + h] = g4;
  }
  __syncthreads();                    // before any atomics — safe

  int lane = threadIdx.x & 63;
  int g    = threadIdx.x >> 4;       // block group 0..15
  int t    = threadIdx.x & 15;
  int base = lane & 48;

  float w0c[16], w1c[16];
  #pragma unroll
  for (int k = 0; k < 16; ++k) {
    w0c[k] = fc0_w1[k * 16 + t];
    w1c[k] = fc1_w1[k * 16 + t];
  }

  const float angc = PI_F / CUT_F;
  int eA = blockIdx.x * 32 + g;
  int eB = eA + 16;
  bool vA = eA < E, vB = eB < E;
  int eAc = vA ? eA : 0, eBc = vB ? eB : 0;

  // ---- phase 1: all input loads ----
  int sA = ei[eAc], dA = ei[E + eAc];
  int sB = ei[eBc], dB = ei[E + eBc];
  float sxA = coords[3 * sA + 0], syA = coords[3 * sA + 1], szA = coords[3 * sA + 2];
  float dxA = coords[3 * dA + 0], dyA = coords[3 * dA + 1], dzA = coords[3 * dA + 2];
  float sxB = coords[3 * sB + 0], syB = coords[3 * sB + 1], szB = coords[3 * sB + 2];
  float dxB = coords[3 * dB + 0], dyB = coords[3 * dB + 1], dzB = coords[3 * dB + 2];
  int aA = an[sA], aB = an[sB];

  // ---- phase 2: geometry; ubuf stores go out immediately ----
  float vxA = sxA - dxA, vyA = syA - dyA, vzA = szA - dzA;
  float vxB = sxB - dxB, vyB = syB - dyB, vzB = szB - dzB;
  float distA = sqrtf(vxA * vxA + vyA * vyA + vzA * vzA);
  float distB = sqrtf(vxB * vxB + vyB * vyB + vzB * vzB);
  float ivA = 1.0f / fmaxf(distA, 1e-9f);
  float ivB = 1.0f / fmaxf(distB, 1e-9f);
  float uxA = vxA * ivA, uyA = vyA * ivA, uzA = vzA * ivA;
  float uxB = vxB * ivB, uyB = vyB * ivB, uzB = vzB * ivB;
  float bcA = (distA < CUT_F) ? (BASIS_C * ivA) : 0.0f;
  float bcB = (distB < CUT_F) ? (BASIS_C * ivB) : 0.0f;

  if (t == 0) {
    if (vA) ubuf[eA] = make_float4(uxA, uyA, uzA, 0.f);
    if (vB) ubuf[eB] = make_float4(uxB, uyB, uzB, 0.f);
  }

  // ---- phase 3: interleaved sine recurrences (shared sines, both heads) ----
  float angA = angc * distA, angB = angc * distB;
  float scA = __sinf(angA), twA = 2.0f * __cosf(angA), spA = 0.f;
  float scB = __sinf(angB), twB = 2.0f * __cosf(angB), spB = 0.f;
  float a0A = 0.f, a1A = 0.f, a0B = 0.f, a1B = 0.f;
  #pragma unroll
  for (int k = 0; k < 16; ++k) {
    a0A = fmaf(scA, w0c[k], a0A);
    a1A = fmaf(scA, w1c[k], a1A);
    a0B = fmaf(scB, w0c[k], a0B);
    a1B = fmaf(scB, w1c[k], a1B);
    float snA = fmaf(twA, scA, -spA); spA = scA; scA = snA;
    float snB = fmaf(twB, scB, -spB); spB = scB; scB = snB;
  }
  float h0A = silu_fast(a0A * bcA * 0.25f);
  float h1A = silu_fast(a1A * bcA * 0.25f);
  float h0B = silu_fast(a0B * bcB * 0.25f);
  float h1B = silu_fast(a1B * bcB * 0.25f);

  // ---- phase 4: interleaved TI loads + contraction ----
  const float2* tpA = (const float2*)(TI + aA * 512) + t;
  const float2* tpB = (const float2*)(TI + aB * 512) + t;
  float u0A = 0.f, u1A = 0.f, u0B = 0.f, u1B = 0.f;
  #pragma unroll
  for (int j = 0; j < 16; ++j) {
    float hjA = __shfl(h0A, base + j, 64);
    float hjB = __shfl(h0B, base + j, 64);
    float2 TA = tpA[j * 16];
    float2 TB = tpB[j * 16];
    u0A = fmaf(hjA, TA.x, u0A);
    u1A = fmaf(hjA, TA.y, u1A);
    u0B = fmaf(hjB, TB.x, u0B);
    u1B = fmaf(hjB, TB.y, u1B);
  }

  // ---- phase 4b: H1/H4 G-transform (16 shuffles + 64 FMA, LDS G-rows) ----
  float H1A = 0.f, H4A = 0.f, H1B = 0.f, H4B = 0.f;
  #pragma unroll
  for (int k = 0; k < 16; ++k) {
    float hbA = __shfl(h1A, base + k, 64);
    float hbB = __shfl(h1B, base + k, 64);
    float G1k = ggs[k * 16 + t];
    float G4k = ggs[256 + k * 16 + t];
    H1A = fmaf(G1k, hbA, H1A);
    H4A = fmaf(G4k, hbA, H4A);
    H1B = fmaf(G1k, hbB, H1B);
    H4B = fmaf(G4k, hbB, H4B);
  }
  if (vA) hbuf2[(size_t)eA * 16 + t] = make_float2(H1A, H4A);
  if (vB) hbuf2[(size_t)eB * 16 + t] = make_float2(H1B, H4B);

  // ---- phase 5: z-side atomics, interleaved layout (fire-and-forget) ----
  if (vA) {
    float* za = zacc + (size_t)dA * 64 + 4 * t;
    float m1 = K1_F * u1A;
    unsafeAtomicAdd(za,     K0_F * u0A);
    unsafeAtomicAdd(za + 1, m1 * uxA);
    unsafeAtomicAdd(za + 2, m1 * uyA);
    unsafeAtomicAdd(za + 3, m1 * uzA);
  }
  if (vB) {
    float* zb = zacc + (size_t)dB * 64 + 4 * t;
    float m1 = K1_F * u1B;
    unsafeAtomicAdd(zb,     K0_F * u0B);
    unsafeAtomicAdd(zb + 1, m1 * uxB);
    unsafeAtomicAdd(zb + 2, m1 * uyB);
    unsafeAtomicAdd(zb + 3, m1 * uzB);
  }
}

// ---------------------------------------------------------------------------
// edge2_kernel: pure streaming sweep. Per edge per lane t:
//   ei[src] + hbuf2 float2 (coalesced) + ubuf float4 (broadcast) +
//   zacc[src] float4 gather (interleaved layout) + 5 FMA:
//   c3 += H1*z0 + H4*(u . zvec)
// Plus readout term: cr = sum_n zacc[n*64+4t] -> 0.25*rr*cr.
// No trig, no shuffles, no LDS except the final reduce.
// ---------------------------------------------------------------------------
__global__ void __launch_bounds__(256)
edge2_kernel(const int* __restrict__ ei,
             const float4* __restrict__ ubuf,
             const float2* __restrict__ hbuf2,
             const float* __restrict__ zacc,
             const float* __restrict__ w_readout,
             float* __restrict__ out,
             int N, int E) {
  int t    = threadIdx.x & 15;
  int ggid = blockIdx.x * 16 + (threadIdx.x >> 4);
  int ngroups = gridDim.x * 16;
  float rr = w_readout[t];

  // readout term: z0 channel t of every node (L2-resident)
  float cr = 0.f;
  for (int n = ggid; n < N; n += ngroups) {
    cr += zacc[(size_t)n * 64 + 4 * t];
  }

  float c3 = 0.f;
  for (int e0 = ggid; e0 < E; e0 += 2 * ngroups) {
    int eA = e0;
    int eB = e0 + ngroups;
    bool vB = eB < E;
    int eBc = vB ? eB : eA;

    int sA = ei[eA], sB = ei[eBc];
    float4 uA = ubuf[eA];
    float4 uB = ubuf[eBc];
    float2 hA = hbuf2[(size_t)eA * 16 + t];
    float2 hB = hbuf2[(size_t)eBc * 16 + t];
    float4 zA = *reinterpret_cast<const float4*>(zacc + (size_t)sA * 64 + 4 * t);
    float4 zB = *reinterpret_cast<const float4*>(zacc + (size_t)sB * 64 + 4 * t);

    float wA = fmaf(uA.x, zA.y, fmaf(uA.y, zA.z, uA.z * zA.w));
    c3 = fmaf(hA.x, zA.x, fmaf(hA.y, wA, c3));
    if (vB) {
      float wB = fmaf(uB.x, zB.y, fmaf(uB.y, zB.z, uB.z * zB.w));
      c3 = fmaf(hB.x, zB.x, fmaf(hB.y, wB, c3));
    }
  }

  float tot = block_reduce_sum(fmaf(c3, P2SC, 0.25f * rr * cr));
  if (threadIdx.x == 0) atomicAdd(out, tot);
}

extern "C" void kernel_launch(void* const* d_in, const int* in_sizes, int n_in,
                              void* d_out, int out_size, void* d_ws, size_t ws_size,
                              hipStream_t stream) {
  const int*   an        = (const int*)d_in[0];
  const float* coords    = (const float*)d_in[1];
  const int*   ei        = (const int*)d_in[2];
  const float* atom_emb  = (const float*)d_in[3];
  const float* fc0_w1    = (const float*)d_in[4];
  const float* fc0_w2    = (const float*)d_in[5];
  const float* fc1_w1    = (const float*)d_in[6];
  const float* fc1_w2    = (const float*)d_in[7];
  const float* w_readout = (const float*)d_in[8];

  int N = in_sizes[0];
  int E = in_sizes[2] / 2;

  // ws layout (16B-aligned first): ubuf E float4, hbuf2 E*16 float2,
  // zacc N*64 (offset 144E bytes -> 16B aligned for any E), TI.
  float4* ubuf  = (float4*)d_ws;                    // E      (2.6 MB)
  float2* hbuf2 = (float2*)(ubuf + E);              // E*16   (20.5 MB)
  float*  zacc  = (float*)(hbuf2 + (size_t)E * 16); // N*64   (2.6 MB)
  float*  TI    = zacc + (size_t)N * 64;            // 100*512
  float*  out   = (float*)d_out;

  int NZ4 = N * 16;                                 // zacc as float4
  int zblocks = (NZ4 + 255) / 256;
  table_kernel<<<NATOMS + zblocks, 256, 0, stream>>>(
      atom_emb, fc0_w2, TI, (float4*)zacc, out, NZ4);

  edge_kernel<<<(E + 31) / 32, 256, 0, stream>>>(
      ei, coords, an, TI, fc0_w1, fc1_w1, fc1_w2, w_readout,
      zacc, hbuf2, ubuf, E);

  edge2_kernel<<<2048, 256, 0, stream>>>(
      ei, ubuf, hbuf2, zacc, w_readout, out, N, E);
}

// Round 11
// 166.789 us; speedup vs baseline: 1.5478x; 1.5478x over previous
//
#include <hip/hip_runtime.h>
#include <math.h>

// EquiTritonModel: N=10000 nodes, E=160000 edges, D=32, H=16, NB=16.
// R23 -> R24: R23's 155us edge_kernel was the zacc layout, not the
// H-precompute: interleaved [n*64+4t+c] scattered each wave-atomic's 16
// lanes at 16B stride => TCC charged ~16B/dword (WRITE_SIZE 182.5MB =
// 40MB * 4 + stores). Atomic cost is governed by per-instruction address
// CONTIGUITY. Fix: planar zacc [n*64 + {t,16+t,32+t,48+t}] (R19-verified
// 40MB) everywhere; keep H1/H4 precompute in edge1 + streaming edge2.
//   K1 table : TI + zero zacc + zero out
//   K2 edge1 : geometry, both MLP heads, TI contraction, H1/H4
//              G-transform (LDS G built BEFORE atomics), stores
//              hbuf2 (float2/lane-edge) + ubuf (float4/edge),
//              4 planar atomics/lane-edge into zacc.
//   K3 edge2 : pure stream: ei[src], hbuf2, ubuf, 4 planar z gathers,
//              5 FMA; readout term folded in.

namespace {
constexpr int   NATOMS   = 100;
constexpr float PI_F     = 3.14159265358979323846f;
constexpr float INV4PI_F = 0.28209479177387814f;   // 1/sqrt(4*pi)
constexpr float SQRT3_F  = 1.7320508075688772f;
constexpr float CUT_F    = 6.0f;
constexpr float BASIS_C  = 2.3094010767585034f;    // sqrt(2/6)*sqrt(16)
constexpr float N0_F     = 0.17677669529663687f;   // 1/sqrt(32)
constexpr float K0_F = INV4PI_F * N0_F * 0.0625f;  // z0 scale incl /DEG
constexpr float K1_F = SQRT3_F * INV4PI_F * N0_F * 0.0625f;
constexpr float P2SC = INV4PI_F * N0_F * (1.0f / 64.0f);
}

__device__ __forceinline__ float silu_fast(float x) {
  return x / (1.0f + __expf(-x));
}

__device__ __forceinline__ float block_reduce_sum(float v) {
  #pragma unroll
  for (int o = 32; o > 0; o >>= 1) v += __shfl_down(v, o, 64);
  __shared__ float ls[8];
  int lane = threadIdx.x & 63;
  int w    = threadIdx.x >> 6;
  if (lane == 0) ls[w] = v;
  __syncthreads();
  float s = 0.f;
  if (threadIdx.x == 0) {
    int nw = (blockDim.x + 63) >> 6;
    for (int i = 0; i < nw; ++i) s += ls[i];
  }
  return s;
}

// ---------------------------------------------------------------------------
// table_kernel: blocks [0,NATOMS) -> TI tables; blocks >= NATOMS zero zacc
// (N*64 floats as float4) — no hipMemset needed.
// ---------------------------------------------------------------------------
__global__ void __launch_bounds__(256)
table_kernel(const float* __restrict__ atom_emb,
             const float* __restrict__ fc0_w2,
             float* __restrict__ TI,
             float4* __restrict__ zero4,   // zacc as float4
             float* __restrict__ out,
             int NZ4) {
  int b = blockIdx.x;
  int tt = threadIdx.x;
  if (b < NATOMS) {
    int j = tt >> 4;
    int h = tt & 15;
    float s0 = 0.f, s1 = 0.f;
    #pragma unroll
    for (int d = 0; d < 32; ++d) {
      float x = atom_emb[b * 32 + d];
      s0 = fmaf(x, fc0_w2[j * 1024 + d * 16 + h], s0);
      s1 = fmaf(x, fc0_w2[j * 1024 + 512 + d * 16 + h], s1);
    }
    TI[b * 512 + j * 32 + 2 * h]     = s0;
    TI[b * 512 + j * 32 + 2 * h + 1] = s1;
    if (b == 0 && tt == 0) *out = 0.f;
  } else {
    int idx = (b - NATOMS) * 256 + tt;
    if (idx < NZ4) zero4[idx] = make_float4(0.f, 0.f, 0.f, 0.f);
  }
}

// ---------------------------------------------------------------------------
// edge_kernel: 16 groups x 16 lanes; group g handles edges b*32+g and
// b*32+16+g (2-edge ILP pipeline). Both MLP heads (shared sines), TI
// contraction, per-edge H1/H4 G-transform. Outputs:
//   zacc[dst*64 + {t,16+t,32+t,48+t}] += {K0*u0, m1*ux, m1*uy, m1*uz}
//     (PLANAR layout: each wave-atomic's 16 lanes contiguous => line-
//      coalesced RMW, 4B/dword effective — the R23 lesson)
//   hbuf2[e*16+t] = (H1,H4)   (coalesced float2)
//   ubuf[e]       = unit vec  (float4, t==0)
// ---------------------------------------------------------------------------
__global__ void __launch_bounds__(256)
edge_kernel(const int* __restrict__ ei,
            const float* __restrict__ coords,
            const int* __restrict__ an,
            const float* __restrict__ TI,
            const float* __restrict__ fc0_w1,
            const float* __restrict__ fc1_w1,
            const float* __restrict__ fc1_w2,
            const float* __restrict__ w_readout,
            float* __restrict__ zacc,
            float2* __restrict__ hbuf2,
            float4* __restrict__ ubuf,
            int E) {
  // G-tables, k-major: ggs[k*16+h] = G1[h,k]; ggs[256+k*16+h] = G4[h,k]
  __shared__ float ggs[512];
  {
    int m = threadIdx.x >> 4;         // hidden index k
    int h = threadIdx.x & 15;
    float g1 = 0.f, g4 = 0.f;
    #pragma unroll
    for (int k = 0; k < 16; ++k) {
      float r = w_readout[k];
      g1 = fmaf(fc1_w2[m * 1024 + h * 16 + k], r, g1);
      g4 = fmaf(fc1_w2[m * 1024 + 768 + h * 16 + k], r, g4);
    }
    ggs[m * 16 + h]       = g1;
    ggs[256 + m * 16 + h] = g4;
  }
  __syncthreads();                    // before any atomics — safe

  int lane = threadIdx.x & 63;
  int g    = threadIdx.x >> 4;       // block group 0..15
  int t    = threadIdx.x & 15;
  int base = lane & 48;

  float w0c[16], w1c[16];
  #pragma unroll
  for (int k = 0; k < 16; ++k) {
    w0c[k] = fc0_w1[k * 16 + t];
    w1c[k] = fc1_w1[k * 16 + t];
  }

  const float angc = PI_F / CUT_F;
  int eA = blockIdx.x * 32 + g;
  int eB = eA + 16;
  bool vA = eA < E, vB = eB < E;
  int eAc = vA ? eA : 0, eBc = vB ? eB : 0;

  // ---- phase 1: all input loads ----
  int sA = ei[eAc], dA = ei[E + eAc];
  int sB = ei[eBc], dB = ei[E + eBc];
  float sxA = coords[3 * sA + 0], syA = coords[3 * sA + 1], szA = coords[3 * sA + 2];
  float dxA = coords[3 * dA + 0], dyA = coords[3 * dA + 1], dzA = coords[3 * dA + 2];
  float sxB = coords[3 * sB + 0], syB = coords[3 * sB + 1], szB = coords[3 * sB + 2];
  float dxB = coords[3 * dB + 0], dyB = coords[3 * dB + 1], dzB = coords[3 * dB + 2];
  int aA = an[sA], aB = an[sB];

  // ---- phase 2: geometry; ubuf stores go out immediately ----
  float vxA = sxA - dxA, vyA = syA - dyA, vzA = szA - dzA;
  float vxB = sxB - dxB, vyB = syB - dyB, vzB = szB - dzB;
  float distA = sqrtf(vxA * vxA + vyA * vyA + vzA * vzA);
  float distB = sqrtf(vxB * vxB + vyB * vyB + vzB * vzB);
  float ivA = 1.0f / fmaxf(distA, 1e-9f);
  float ivB = 1.0f / fmaxf(distB, 1e-9f);
  float uxA = vxA * ivA, uyA = vyA * ivA, uzA = vzA * ivA;
  float uxB = vxB * ivB, uyB = vyB * ivB, uzB = vzB * ivB;
  float bcA = (distA < CUT_F) ? (BASIS_C * ivA) : 0.0f;
  float bcB = (distB < CUT_F) ? (BASIS_C * ivB) : 0.0f;

  if (t == 0) {
    if (vA) ubuf[eA] = make_float4(uxA, uyA, uzA, 0.f);
    if (vB) ubuf[eB] = make_float4(uxB, uyB, uzB, 0.f);
  }

  // ---- phase 3: interleaved sine recurrences (shared sines, both heads) ----
  float angA = angc * distA, angB = angc * distB;
  float scA = __sinf(angA), twA = 2.0f * __cosf(angA), spA = 0.f;
  float scB = __sinf(angB), twB = 2.0f * __cosf(angB), spB = 0.f;
  float a0A = 0.f, a1A = 0.f, a0B = 0.f, a1B = 0.f;
  #pragma unroll
  for (int k = 0; k < 16; ++k) {
    a0A = fmaf(scA, w0c[k], a0A);
    a1A = fmaf(scA, w1c[k], a1A);
    a0B = fmaf(scB, w0c[k], a0B);
    a1B = fmaf(scB, w1c[k], a1B);
    float snA = fmaf(twA, scA, -spA); spA = scA; scA = snA;
    float snB = fmaf(twB, scB, -spB); spB = scB; scB = snB;
  }
  float h0A = silu_fast(a0A * bcA * 0.25f);
  float h1A = silu_fast(a1A * bcA * 0.25f);
  float h0B = silu_fast(a0B * bcB * 0.25f);
  float h1B = silu_fast(a1B * bcB * 0.25f);

  // ---- phase 4: interleaved TI loads + contraction ----
  const float2* tpA = (const float2*)(TI + aA * 512) + t;
  const float2* tpB = (const float2*)(TI + aB * 512) + t;
  float u0A = 0.f, u1A = 0.f, u0B = 0.f, u1B = 0.f;
  #pragma unroll
  for (int j = 0; j < 16; ++j) {
    float hjA = __shfl(h0A, base + j, 64);
    float hjB = __shfl(h0B, base + j, 64);
    float2 TA = tpA[j * 16];
    float2 TB = tpB[j * 16];
    u0A = fmaf(hjA, TA.x, u0A);
    u1A = fmaf(hjA, TA.y, u1A);
    u0B = fmaf(hjB, TB.x, u0B);
    u1B = fmaf(hjB, TB.y, u1B);
  }

  // ---- phase 4b: H1/H4 G-transform (16 shuffles + 64 FMA, LDS G-rows) ----
  float H1A = 0.f, H4A = 0.f, H1B = 0.f, H4B = 0.f;
  #pragma unroll
  for (int k = 0; k < 16; ++k) {
    float hbA = __shfl(h1A, base + k, 64);
    float hbB = __shfl(h1B, base + k, 64);
    float G1k = ggs[k * 16 + t];
    float G4k = ggs[256 + k * 16 + t];
    H1A = fmaf(G1k, hbA, H1A);
    H4A = fmaf(G4k, hbA, H4A);
    H1B = fmaf(G1k, hbB, H1B);
    H4B = fmaf(G4k, hbB, H4B);
  }
  if (vA) hbuf2[(size_t)eA * 16 + t] = make_float2(H1A, H4A);
  if (vB) hbuf2[(size_t)eB * 16 + t] = make_float2(H1B, H4B);

  // ---- phase 5: planar z-side atomics (fire-and-forget, coalesced) ----
  if (vA) {
    float* za = zacc + (size_t)dA * 64 + t;
    float m1 = K1_F * u1A;
    unsafeAtomicAdd(za,      K0_F * u0A);
    unsafeAtomicAdd(za + 16, m1 * uxA);
    unsafeAtomicAdd(za + 32, m1 * uyA);
    unsafeAtomicAdd(za + 48, m1 * uzA);
  }
  if (vB) {
    float* zb = zacc + (size_t)dB * 64 + t;
    float m1 = K1_F * u1B;
    unsafeAtomicAdd(zb,      K0_F * u0B);
    unsafeAtomicAdd(zb + 16, m1 * uxB);
    unsafeAtomicAdd(zb + 32, m1 * uyB);
    unsafeAtomicAdd(zb + 48, m1 * uzB);
  }
}

// ---------------------------------------------------------------------------
// edge2_kernel: pure streaming sweep. Per edge per lane t:
//   ei[src] + hbuf2 float2 (coalesced) + ubuf float4 (broadcast) +
//   4 planar zacc[src] gathers (each a 64B group segment) + 5 FMA:
//   c3 += H1*z0 + H4*(u . zvec)
// Plus readout term: cr = sum_n zacc[n*64+t] -> 0.25*rr*cr.
// No trig, no shuffles, no LDS except the final reduce.
// ---------------------------------------------------------------------------
__global__ void __launch_bounds__(256)
edge2_kernel(const int* __restrict__ ei,
             const float4* __restrict__ ubuf,
             const float2* __restrict__ hbuf2,
             const float* __restrict__ zacc,
             const float* __restrict__ w_readout,
             float* __restrict__ out,
             int N, int E) {
  int t    = threadIdx.x & 15;
  int ggid = blockIdx.x * 16 + (threadIdx.x >> 4);
  int ngroups = gridDim.x * 16;
  float rr = w_readout[t];

  // readout term: z0 channel t of every node (L2-resident)
  float cr = 0.f;
  for (int n = ggid; n < N; n += ngroups) {
    cr += zacc[(size_t)n * 64 + t];
  }

  float c3 = 0.f;
  for (int e0 = ggid; e0 < E; e0 += 2 * ngroups) {
    int eA = e0;
    int eB = e0 + ngroups;
    bool vB = eB < E;
    int eBc = vB ? eB : eA;

    int sA = ei[eA], sB = ei[eBc];
    float4 uA = ubuf[eA];
    float4 uB = ubuf[eBc];
    float2 hA = hbuf2[(size_t)eA * 16 + t];
    float2 hB = hbuf2[(size_t)eBc * 16 + t];
    size_t qa = (size_t)sA * 64;
    size_t qb = (size_t)sB * 64;
    float z0A = zacc[qa + t],      z0B = zacc[qb + t];
    float zxA = zacc[qa + 16 + t], zxB = zacc[qb + 16 + t];
    float zyA = zacc[qa + 32 + t], zyB = zacc[qb + 32 + t];
    float zzA = zacc[qa + 48 + t], zzB = zacc[qb + 48 + t];

    float wA = fmaf(uA.x, zxA, fmaf(uA.y, zyA, uA.z * zzA));
    c3 = fmaf(hA.x, z0A, fmaf(hA.y, wA, c3));
    if (vB) {
      float wB = fmaf(uB.x, zxB, fmaf(uB.y, zyB, uB.z * zzB));
      c3 = fmaf(hB.x, z0B, fmaf(hB.y, wB, c3));
    }
  }

  float tot = block_reduce_sum(fmaf(c3, P2SC, 0.25f * rr * cr));
  if (threadIdx.x == 0) atomicAdd(out, tot);
}

extern "C" void kernel_launch(void* const* d_in, const int* in_sizes, int n_in,
                              void* d_out, int out_size, void* d_ws, size_t ws_size,
                              hipStream_t stream) {
  const int*   an        = (const int*)d_in[0];
  const float* coords    = (const float*)d_in[1];
  const int*   ei        = (const int*)d_in[2];
  const float* atom_emb  = (const float*)d_in[3];
  const float* fc0_w1    = (const float*)d_in[4];
  const float* fc0_w2    = (const float*)d_in[5];
  const float* fc1_w1    = (const float*)d_in[6];
  const float* fc1_w2    = (const float*)d_in[7];
  const float* w_readout = (const float*)d_in[8];

  int N = in_sizes[0];
  int E = in_sizes[2] / 2;

  // ws layout (16B-aligned first): ubuf E float4, hbuf2 E*16 float2,
  // zacc N*64, TI.
  float4* ubuf  = (float4*)d_ws;                    // E      (2.6 MB)
  float2* hbuf2 = (float2*)(ubuf + E);              // E*16   (20.5 MB)
  float*  zacc  = (float*)(hbuf2 + (size_t)E * 16); // N*64   (2.6 MB)
  float*  TI    = zacc + (size_t)N * 64;            // 100*512
  float*  out   = (float*)d_out;

  int NZ4 = N * 16;                                 // zacc as float4
  int zblocks = (NZ4 + 255) / 256;
  table_kernel<<<NATOMS + zblocks, 256, 0, stream>>>(
      atom_emb, fc0_w2, TI, (float4*)zacc, out, NZ4);

  edge_kernel<<<(E + 31) / 32, 256, 0, stream>>>(
      ei, coords, an, TI, fc0_w1, fc1_w1, fc1_w2, w_readout,
      zacc, hbuf2, ubuf, E);

  edge2_kernel<<<2048, 256, 0, stream>>>(
      ei, ubuf, hbuf2, zacc, w_readout, out, N, E);
}

// Round 12
// 148.457 us; speedup vs baseline: 1.7389x; 1.1235x over previous
//
#include <hip/hip_runtime.h>
#include <math.h>

// EquiTritonModel: N=10000 nodes, E=160000 edges, D=32, H=16, NB=16.
// R24 -> R25: R24 confirmed edge1 runs at flat ~1 TB/s effective write
// throughput (store/atomic mix irrelevant); H-precompute reverted.
// Discriminating experiment on the atomic wall: line-RMW-bound (40MB
// irreducible) vs request-rate-bound. Phase 5 restructured so ONE
// wave-atomic instruction covers one edge's 64 CONTIGUOUS dwords
// (4 lines) instead of 4 instructions x 16 lanes: 7 shuffles
// redistribute {dst,u0,u1,u} across the wave (lane = 16*comp + t), then
// a single unsafeAtomicAdd(zacc + dst*64 + lane). Atomic instruction
// count 4x down (32->8/wave), line traffic unchanged. Everything else
// byte-identical to R19 (42.3us edge1, 148.4 total).
// Pre-commit: null => declare roofline (fixed ~60us harness floor +
// 40MB line-RMW atomic cost).

namespace {
constexpr int   NATOMS   = 100;
constexpr float PI_F     = 3.14159265358979323846f;
constexpr float INV4PI_F = 0.28209479177387814f;   // 1/sqrt(4*pi)
constexpr float SQRT3_F  = 1.7320508075688772f;
constexpr float CUT_F    = 6.0f;
constexpr float BASIS_C  = 2.3094010767585034f;    // sqrt(2/6)*sqrt(16)
constexpr float N0_F     = 0.17677669529663687f;   // 1/sqrt(32)
constexpr float K0_F = INV4PI_F * N0_F * 0.0625f;  // z0 scale incl /DEG
constexpr float K1_F = SQRT3_F * INV4PI_F * N0_F * 0.0625f;
constexpr float P2SC = INV4PI_F * N0_F * (1.0f / 64.0f);
}

__device__ __forceinline__ float silu_fast(float x) {
  return x / (1.0f + __expf(-x));
}

__device__ __forceinline__ float block_reduce_sum(float v) {
  #pragma unroll
  for (int o = 32; o > 0; o >>= 1) v += __shfl_down(v, o, 64);
  __shared__ float ls[8];
  int lane = threadIdx.x & 63;
  int w    = threadIdx.x >> 6;
  if (lane == 0) ls[w] = v;
  __syncthreads();
  float s = 0.f;
  if (threadIdx.x == 0) {
    int nw = (blockDim.x + 63) >> 6;
    for (int i = 0; i < nw; ++i) s += ls[i];
  }
  return s;
}

// ---------------------------------------------------------------------------
// table_kernel: blocks [0,NATOMS) -> TI tables; blocks >= NATOMS zero zacc
// (N*64 floats as float4) — no hipMemset needed.
// ---------------------------------------------------------------------------
__global__ void __launch_bounds__(256)
table_kernel(const float* __restrict__ atom_emb,
             const float* __restrict__ fc0_w2,
             float* __restrict__ TI,
             float4* __restrict__ zero4,   // zacc as float4
             float* __restrict__ out,
             int NZ4) {
  int b = blockIdx.x;
  int tt = threadIdx.x;
  if (b < NATOMS) {
    int j = tt >> 4;
    int h = tt & 15;
    float s0 = 0.f, s1 = 0.f;
    #pragma unroll
    for (int d = 0; d < 32; ++d) {
      float x = atom_emb[b * 32 + d];
      s0 = fmaf(x, fc0_w2[j * 1024 + d * 16 + h], s0);
      s1 = fmaf(x, fc0_w2[j * 1024 + 512 + d * 16 + h], s1);
    }
    TI[b * 512 + j * 32 + 2 * h]     = s0;
    TI[b * 512 + j * 32 + 2 * h + 1] = s1;
    if (b == 0 && tt == 0) *out = 0.f;
  } else {
    int idx = (b - NATOMS) * 256 + tt;
    if (idx < NZ4) zero4[idx] = make_float4(0.f, 0.f, 0.f, 0.f);
  }
}

// ---------------------------------------------------------------------------
// edge_kernel: 16 groups x 16 lanes; group g handles edges b*32+g and
// b*32+16+g (2-edge ILP pipeline). Phase 5 = wave-cooperative atomics:
// one wave-atomic instruction per edge (64 contiguous dwords), 8 per
// wave instead of 32. No LDS, no barrier, no out atomic.
// ---------------------------------------------------------------------------
__global__ void __launch_bounds__(256)
edge_kernel(const int* __restrict__ ei,
            const float* __restrict__ coords,
            const int* __restrict__ an,
            const float* __restrict__ TI,
            const float* __restrict__ fc0_w1,
            float* __restrict__ zacc,
            int E) {
  int lane = threadIdx.x & 63;
  int g    = threadIdx.x >> 4;       // block group 0..15
  int t    = threadIdx.x & 15;
  int base = lane & 48;

  float w0c[16];
  #pragma unroll
  for (int k = 0; k < 16; ++k) w0c[k] = fc0_w1[k * 16 + t];

  const float angc = PI_F / CUT_F;
  int eA = blockIdx.x * 32 + g;
  int eB = eA + 16;
  bool vA = eA < E, vB = eB < E;
  int eAc = vA ? eA : 0, eBc = vB ? eB : 0;

  // ---- phase 1: all input loads ----
  int sA = ei[eAc], dA = ei[E + eAc];
  int sB = ei[eBc], dB = ei[E + eBc];
  float sxA = coords[3 * sA + 0], syA = coords[3 * sA + 1], szA = coords[3 * sA + 2];
  float dxA = coords[3 * dA + 0], dyA = coords[3 * dA + 1], dzA = coords[3 * dA + 2];
  float sxB = coords[3 * sB + 0], syB = coords[3 * sB + 1], szB = coords[3 * sB + 2];
  float dxB = coords[3 * dB + 0], dyB = coords[3 * dB + 1], dzB = coords[3 * dB + 2];
  int aA = an[sA], aB = an[sB];

  // ---- phase 2: geometry ----
  float vxA = sxA - dxA, vyA = syA - dyA, vzA = szA - dzA;
  float vxB = sxB - dxB, vyB = syB - dyB, vzB = szB - dzB;
  float distA = sqrtf(vxA * vxA + vyA * vyA + vzA * vzA);
  float distB = sqrtf(vxB * vxB + vyB * vyB + vzB * vzB);
  float ivA = 1.0f / fmaxf(distA, 1e-9f);
  float ivB = 1.0f / fmaxf(distB, 1e-9f);
  float uxA = vxA * ivA, uyA = vyA * ivA, uzA = vzA * ivA;
  float uxB = vxB * ivB, uyB = vyB * ivB, uzB = vzB * ivB;
  float bcA = (distA < CUT_F) ? (BASIS_C * ivA) : 0.0f;
  float bcB = (distB < CUT_F) ? (BASIS_C * ivB) : 0.0f;

  // ---- phase 3: interleaved sine recurrences (h0 only) ----
  float angA = angc * distA, angB = angc * distB;
  float scA = __sinf(angA), twA = 2.0f * __cosf(angA), spA = 0.f;
  float scB = __sinf(angB), twB = 2.0f * __cosf(angB), spB = 0.f;
  float a0A = 0.f, a0B = 0.f;
  #pragma unroll
  for (int k = 0; k < 16; ++k) {
    a0A = fmaf(scA, w0c[k], a0A);
    a0B = fmaf(scB, w0c[k], a0B);
    float snA = fmaf(twA, scA, -spA); spA = scA; scA = snA;
    float snB = fmaf(twB, scB, -spB); spB = scB; scB = snB;
  }
  float h0A = silu_fast(a0A * bcA * 0.25f);
  float h0B = silu_fast(a0B * bcB * 0.25f);

  // ---- phase 4: interleaved TI loads + contraction ----
  const float2* tpA = (const float2*)(TI + aA * 512) + t;
  const float2* tpB = (const float2*)(TI + aB * 512) + t;
  float u0A = 0.f, u1A = 0.f, u0B = 0.f, u1B = 0.f;
  #pragma unroll
  for (int j = 0; j < 16; ++j) {
    float hjA = __shfl(h0A, base + j, 64);
    float hjB = __shfl(h0B, base + j, 64);
    float2 TA = tpA[j * 16];
    float2 TB = tpB[j * 16];
    u0A = fmaf(hjA, TA.x, u0A);
    u1A = fmaf(hjA, TA.y, u1A);
    u0B = fmaf(hjB, TB.x, u0B);
    u1B = fmaf(hjB, TB.y, u1B);
  }

  // ---- phase 5: wave-cooperative z-side atomics ----
  // Wave w's 4 groups hold edges blockIdx*32 + 4w + {0..3} (A slot) and
  // +16 (B slot). For edge j-of-wave: lane l = 16*comp + lt writes
  // zacc[dst*64 + l] — all 64 dwords of one edge in ONE instruction.
  {
    int wv   = threadIdx.x >> 6;       // wave id 0..3
    int lt   = lane & 15;
    int comp = lane >> 4;              // 0..3
    #pragma unroll
    for (int j = 0; j < 4; ++j) {
      int sl = 16 * j + lt;            // source lane: group j, channel lt
      int ejA = blockIdx.x * 32 + 4 * wv + j;       // wave-uniform
      if (ejA < E) {
        int   dj  = __shfl(dA,  sl, 64);
        float u0j = __shfl(u0A, sl, 64);
        float u1j = __shfl(u1A, sl, 64);
        float uxj = __shfl(uxA, sl, 64);
        float uyj = __shfl(uyA, sl, 64);
        float uzj = __shfl(uzA, sl, 64);
        float uc  = (comp == 1) ? uxj : (comp == 2) ? uyj : uzj;
        float val = (comp == 0) ? (K0_F * u0j) : (K1_F * u1j * uc);
        unsafeAtomicAdd(zacc + (size_t)dj * 64 + lane, val);
      }
      int ejB = ejA + 16;
      if (ejB < E) {
        int   dj  = __shfl(dB,  sl, 64);
        float u0j = __shfl(u0B, sl, 64);
        float u1j = __shfl(u1B, sl, 64);
        float uxj = __shfl(uxB, sl, 64);
        float uyj = __shfl(uyB, sl, 64);
        float uzj = __shfl(uzB, sl, 64);
        float uc  = (comp == 1) ? uxj : (comp == 2) ? uyj : uzj;
        float val = (comp == 0) ? (K0_F * u0j) : (K1_F * u1j * uc);
        unsafeAtomicAdd(zacc + (size_t)dj * 64 + lane, val);
      }
    }
  }
}

// ---------------------------------------------------------------------------
// edge2_kernel: grid-stride 2-edge pipeline (byte-identical to R19).
// Per edge: recompute geometry + h1 recurrence; gather raw zacc[src]
// (4 x 64B); row-form G-transform; c3 += z0[h]*H1[h] + (u.zvec[h])*H4[h].
// Readout term folded in as grid-stride node sum over zacc z0 rows.
// ---------------------------------------------------------------------------
__global__ void __launch_bounds__(256)
edge2_kernel(const int* __restrict__ ei,
             const float* __restrict__ coords,
             const float* __restrict__ zacc,
             const float* __restrict__ fc1_w1,
             const float* __restrict__ fc1_w2,
             const float* __restrict__ w_readout,
             float* __restrict__ out,
             int N, int E) {
  __shared__ float ggs[512];          // [0:256)=G1 rows, [256:512)=G4 rows
  {
    int j = threadIdx.x >> 4;         // hidden index
    int h = threadIdx.x & 15;
    float g1 = 0.f, g4 = 0.f;
    #pragma unroll
    for (int k = 0; k < 16; ++k) {
      float r = w_readout[k];
      g1 = fmaf(fc1_w2[j * 1024 + h * 16 + k], r, g1);
      g4 = fmaf(fc1_w2[j * 1024 + 768 + h * 16 + k], r, g4);
    }
    ggs[h * 16 + j]       = g1;       // G1[h, t=j]
    ggs[256 + h * 16 + j] = g4;       // G4[h, t=j]
  }
  __syncthreads();

  int lane = threadIdx.x & 63;
  int t    = lane & 15;               // this lane's h-row
  int base = lane & 48;

  float g1r[16], g4r[16], w1c[16];
  #pragma unroll
  for (int k = 0; k < 16; ++k) {
    g1r[k] = ggs[t * 16 + k];
    g4r[k] = ggs[256 + t * 16 + k];
    w1c[k] = fc1_w1[k * 16 + t];
  }
  float rr = w_readout[t];

  const float angc = PI_F / CUT_F;
  int ggid = blockIdx.x * 16 + (threadIdx.x >> 4);
  int ngroups = gridDim.x * 16;

  // ---- readout term: sum over nodes of z0 row (L2/L3-resident) ----
  float cr = 0.f;
  for (int n = ggid; n < N; n += ngroups) {
    cr += zacc[(size_t)n * 64 + t];
  }

  // ---- main edge sweep ----
  float c3 = 0.f;
  for (int e0 = ggid; e0 < E; e0 += 2 * ngroups) {
    int eA = e0;
    int eB = e0 + ngroups;
    bool vB = eB < E;
    int eBc = vB ? eB : eA;

    int sA = ei[eA],  dA = ei[E + eA];
    int sB = ei[eBc], dB = ei[E + eBc];
    float sxA = coords[3 * sA + 0], syA = coords[3 * sA + 1], szA = coords[3 * sA + 2];
    float dxA = coords[3 * dA + 0], dyA = coords[3 * dA + 1], dzA = coords[3 * dA + 2];
    float sxB = coords[3 * sB + 0], syB = coords[3 * sB + 1], szB = coords[3 * sB + 2];
    float dxB = coords[3 * dB + 0], dyB = coords[3 * dB + 1], dzB = coords[3 * dB + 2];

    size_t qa = (size_t)sA * 64;
    size_t qb = (size_t)sB * 64;
    float z0A = zacc[qa + t],      z0B = zacc[qb + t];
    float zxA = zacc[qa + 16 + t], zxB = zacc[qb + 16 + t];
    float zyA = zacc[qa + 32 + t], zyB = zacc[qb + 32 + t];
    float zzA = zacc[qa + 48 + t], zzB = zacc[qb + 48 + t];

    float vxA = sxA - dxA, vyA = syA - dyA, vzA = szA - dzA;
    float vxB = sxB - dxB, vyB = syB - dyB, vzB = szB - dzB;
    float distA = sqrtf(vxA * vxA + vyA * vyA + vzA * vzA);
    float distB = sqrtf(vxB * vxB + vyB * vyB + vzB * vzB);
    float ivA = 1.0f / fmaxf(distA, 1e-9f);
    float ivB = 1.0f / fmaxf(distB, 1e-9f);
    float uxA = vxA * ivA, uyA = vyA * ivA, uzA = vzA * ivA;
    float uxB = vxB * ivB, uyB = vyB * ivB, uzB = vzB * ivB;
    float bcA = (distA < CUT_F) ? (BASIS_C * ivA) : 0.0f;
    float bcB = (distB < CUT_F) ? (BASIS_C * ivB) : 0.0f;

    float angA = angc * distA, angB = angc * distB;
    float scA = __sinf(angA), twA = 2.0f * __cosf(angA), spA = 0.f;
    float scB = __sinf(angB), twB = 2.0f * __cosf(angB), spB = 0.f;
    float a1A = 0.f, a1B = 0.f;
    #pragma unroll
    for (int k = 0; k < 16; ++k) {
      a1A = fmaf(scA, w1c[k], a1A);
      a1B = fmaf(scB, w1c[k], a1B);
      float snA = fmaf(twA, scA, -spA); spA = scA; scA = snA;
      float snB = fmaf(twB, scB, -spB); spB = scB; scB = snB;
    }
    float h1A = silu_fast(a1A * bcA * 0.25f);
    float h1B = silu_fast(a1B * bcB * 0.25f);

    float H1A = 0.f, H4A = 0.f, H1B = 0.f, H4B = 0.f;
    #pragma unroll
    for (int k = 0; k < 16; ++k) {
      float hbA = __shfl(h1A, base + k, 64);
      float hbB = __shfl(h1B, base + k, 64);
      H1A = fmaf(g1r[k], hbA, H1A);
      H4A = fmaf(g4r[k], hbA, H4A);
      H1B = fmaf(g1r[k], hbB, H1B);
      H4B = fmaf(g4r[k], hbB, H4B);
    }

    float wA = fmaf(uxA, zxA, fmaf(uyA, zyA, uzA * zzA));
    float wB = fmaf(uxB, zxB, fmaf(uyB, zyB, uzB * zzB));
    c3 = fmaf(H1A, z0A, fmaf(H4A, wA, c3));
    if (vB) c3 = fmaf(H1B, z0B, fmaf(H4B, wB, c3));
  }

  float tot = block_reduce_sum(fmaf(c3, P2SC, 0.25f * rr * cr));
  if (threadIdx.x == 0) atomicAdd(out, tot);
}

extern "C" void kernel_launch(void* const* d_in, const int* in_sizes, int n_in,
                              void* d_out, int out_size, void* d_ws, size_t ws_size,
                              hipStream_t stream) {
  const int*   an        = (const int*)d_in[0];
  const float* coords    = (const float*)d_in[1];
  const int*   ei        = (const int*)d_in[2];
  const float* atom_emb  = (const float*)d_in[3];
  const float* fc0_w1    = (const float*)d_in[4];
  const float* fc0_w2    = (const float*)d_in[5];
  const float* fc1_w1    = (const float*)d_in[6];
  const float* fc1_w2    = (const float*)d_in[7];
  const float* w_readout = (const float*)d_in[8];

  int N = in_sizes[0];
  int E = in_sizes[2] / 2;

  // ws layout (16B-aligned)
  float* zacc = (float*)d_ws;                   // N*64   (2.6 MB)
  float* TI   = zacc + (size_t)N * 64;          // 100*512
  float* out  = (float*)d_out;

  int NZ4 = N * 16;                             // zacc as float4
  int zblocks = (NZ4 + 255) / 256;
  table_kernel<<<NATOMS + zblocks, 256, 0, stream>>>(
      atom_emb, fc0_w2, TI, (float4*)zacc, out, NZ4);

  edge_kernel<<<(E + 31) / 32, 256, 0, stream>>>(
      ei, coords, an, TI, fc0_w1, zacc, E);

  edge2_kernel<<<2048, 256, 0, stream>>>(
      ei, coords, zacc, fc1_w1, fc1_w2, w_readout, out, N, E);
}